// Round 2
// baseline (304.959 us; speedup 1.0000x reference)
//
#include <hip/hip_runtime.h>

// Encoder: 2-layer LSTM (H=16 each), x [B=16384, T=100, I=18], FP32 in/out.
// R8: single-wave R6 structure (R7's producer/consumer split REGRESSED:
// barrier lockstep, combined issue 68.5%->60.5%) + two within-wave fixes:
//  (a) MFMA chain split. R6 ran 4 dependent chains of depth 5 (L1) / 4 (L2);
//      dependent-MFMA latency was exposed, and the x-part of each chain was
//      serialized behind the ew block even though x(t+1) has been ready for
//      2 iterations. R8 issues the x-part (3-deep) and h2-part (2-deep)
//      at the TOP of the iteration (latency hides under ew's ~160cy of
//      transcendentals), then the h/rb-parts (2-deep) after ew, combining
//      with one fp32 vector add per gate. 8 shallow chains in flight
//      instead of 4 deep ones.
//  (b) v_perm_b32 packing: split_pack 5->3 ops, cvt_pair 9->6 ops
//      (-28 VALU/iter, offset by +32 v_add_f32 from the combines).
// One wave per 16-batch tile (1024 waves = 1/SIMD, structural). G^T = W@H^T:
// C/D col=lane&15=batch, row=quad*4+reg=unit; packed (hi|lo<<16) h dwords
// ARE the next step's B-fragment -> recurrence never leaves registers.
// PRECISION: identical two-term trunc splits to R6 (measured 9.77e-4 vs
// 3.9e-3 threshold); partial-sum recombine is a <=1ulp fp32 reorder.

typedef float f32x4 __attribute__((ext_vector_type(4)));
typedef __bf16 bf16x8 __attribute__((ext_vector_type(8)));
typedef unsigned int uint32x4 __attribute__((ext_vector_type(4)));

union FragU { bf16x8 v; unsigned short u[8]; unsigned int d[4]; uint32x4 q; };

#define MFMA16(A, B, C) __builtin_amdgcn_mfma_f32_16x16x32_bf16((A), (B), (C), 0, 0, 0)

static __device__ __forceinline__ unsigned short f2bf(float f) {  // RNE (weights)
  unsigned int u = __builtin_bit_cast(unsigned int, f);
  u = u + 0x7FFFu + ((u >> 16) & 1u);
  return (unsigned short)(u >> 16);
}
static __device__ __forceinline__ float bfbits2f(unsigned short h) {
  unsigned int u = ((unsigned int)h) << 16;
  return __builtin_bit_cast(float, u);
}
static __device__ __forceinline__ float sigm(float x) {
  // 1/(1+exp(-x)); saturates cleanly, never NaN for finite x.
  return __builtin_amdgcn_rcpf(1.0f + __builtin_amdgcn_exp2f(x * -1.4426950408889634f));
}
static __device__ __forceinline__ float tanh_(float x) {
  // 1 - 2/(1+exp(2x)); saturates to +-1.
  return 1.0f - 2.0f * __builtin_amdgcn_rcpf(1.0f + __builtin_amdgcn_exp2f(x * 2.8853900817779268f));
}
// Trunc two-term split packed as (bf_hi | bf_lo<<16), via v_perm_b32:
// D = bytes {l[3],l[2],u[3],u[2]} == (u>>16) | (l & 0xFFFF0000).
static __device__ __forceinline__ unsigned int split_pack(float v) {
  unsigned int u = __builtin_bit_cast(unsigned int, v);
  float hf = __builtin_bit_cast(float, u & 0xFFFF0000u);
  unsigned int l = __builtin_bit_cast(unsigned int, v - hf);
  return __builtin_amdgcn_perm(l, u, 0x07060302u);
}
// Split a float pair into hi-frag dword and lo-frag dword (6 VALU via perm).
static __device__ __forceinline__ void cvt_pair(float f0, float f1,
                                                unsigned int& hd, unsigned int& ld) {
  unsigned int u0 = __builtin_bit_cast(unsigned int, f0);
  unsigned int u1 = __builtin_bit_cast(unsigned int, f1);
  unsigned int h0 = u0 & 0xFFFF0000u;
  unsigned int h1 = u1 & 0xFFFF0000u;
  hd = __builtin_amdgcn_perm(u1, u0, 0x07060302u);
  unsigned int l0 = __builtin_bit_cast(unsigned int, f0 - __builtin_bit_cast(float, h0));
  unsigned int l1 = __builtin_bit_cast(unsigned int, f1 - __builtin_bit_cast(float, h1));
  ld = __builtin_amdgcn_perm(l1, l0, 0x07060302u);
}

struct RawX { float2 a, b2, c, d; };

__global__ __launch_bounds__(256, 1) void enc_kernel(
    const float* __restrict__ x,     // [16384,100,18]
    const float* __restrict__ Wih1,  // [64,18]
    const float* __restrict__ Whh1,  // [64,16]
    const float* __restrict__ bih1,  // [64]
    const float* __restrict__ bhh1,  // [64]
    const float* __restrict__ Wih2,  // [64,16]
    const float* __restrict__ Whh2,  // [64,16]
    const float* __restrict__ bih2,  // [64]
    const float* __restrict__ bhh2,  // [64]
    float* __restrict__ out)         // [16384,16]
{
  const int lane = threadIdx.x & 63;
  const int b    = lane & 15;  // batch in tile: A m-row / B n-col / C col
  const int g    = lane >> 4;  // k-group; C row-quad (units 4g..4g+3)

  const int wid = (int)((blockIdx.x * blockDim.x + threadIdx.x) >> 6);
  const int b0  = wid * 16;

  // ---- loop-invariant weight A-fragments: A[m=lane&15][k=8g+j] ----
  FragU A1h[4], A1l[4], A2h[4], A2l[4], A3h[4], A3l[4], A4h[4], A4l[4];
  f32x4 bias1v[4], bias2v[4];
#pragma unroll
  for (int tn = 0; tn < 4; ++tn) {  // 0=i 1=f 2=g 3=o (PyTorch gate order)
    const int row = tn * 16 + b;
#pragma unroll
    for (int j = 0; j < 8; ++j) {
      const int k = 8 * g + j;
      if (k < 18) {
        const float w = Wih1[row * 18 + k];
        A1h[tn].u[j] = f2bf(w);
        A1l[tn].u[j] = f2bf(w - bfbits2f(A1h[tn].u[j]));
      } else {
        A1h[tn].u[j] = 0;
        A1l[tn].u[j] = 0;
      }
      const int kk = k >> 1;  // hi/lo interleave: both K slots share the weight
      const float w2 = Whh1[row * 16 + kk];
      const float w3 = Wih2[row * 16 + kk];
      const float w4 = Whh2[row * 16 + kk];
      A2h[tn].u[j] = f2bf(w2); A2l[tn].u[j] = f2bf(w2 - bfbits2f(A2h[tn].u[j]));
      A3h[tn].u[j] = f2bf(w3); A3l[tn].u[j] = f2bf(w3 - bfbits2f(A3h[tn].u[j]));
      A4h[tn].u[j] = f2bf(w4); A4l[tn].u[j] = f2bf(w4 - bfbits2f(A4h[tn].u[j]));
    }
#pragma unroll
    for (int r = 0; r < 4; ++r) {
      const int u4 = tn * 16 + 4 * g + r;  // C row = unit 4g+r of gate tn
      bias1v[tn][r] = bih1[u4] + bhh1[u4];
      bias2v[tn][r] = bih2[u4] + bhh2[u4];
    }
  }

  const f32x4 z4 = {0.f, 0.f, 0.f, 0.f};

  // ---- x addressing: lane (b,g) covers x[b0+b][t][8g .. 8g+7] ----
  // g==3 lanes: k=24..31 are all beyond I=18; their B-slots multiply zero
  // weights (A1 pad), so they read a fixed valid address and never advance.
  const float* const x0 = x + (size_t)(b0 + b) * 1800 + 8 * g;
  const int adv = (g == 3) ? 0 : 18;

  auto loadraw = [&](const float* p) -> RawX {
    RawX r;
    r.a = *(const float2*)p;  // g<2: k 8g..8g+1; g==2: k 16,17; g==3: dummy
    if (g < 2) {              // full 8 features, in-bounds for all t
      r.b2 = *(const float2*)(p + 2);
      r.c  = *(const float2*)(p + 4);
      r.d  = *(const float2*)(p + 6);
    } else {                  // g>=2: only pair a matters (k>=18 hits A-pad)
      r.b2 = r.c = r.d = make_float2(0.f, 0.f);
    }
    return r;
  };
  auto cvt = [&](const RawX& rw_, FragU& hi, FragU& lo) {
    cvt_pair(rw_.a.x, rw_.a.y, hi.d[0], lo.d[0]);
    cvt_pair(rw_.b2.x, rw_.b2.y, hi.d[1], lo.d[1]);
    cvt_pair(rw_.c.x, rw_.c.y, hi.d[2], lo.d[2]);
    cvt_pair(rw_.d.x, rw_.d.y, hi.d[3], lo.d[3]);
  };

  // ---- prologue: raw x for t=0,1,2 in flight together ----
  RawX rw0 = loadraw(x0);
  RawX rw1 = loadraw(x0 + adv);
  RawX rw  = loadraw(x0 + 2 * adv);
  const float* xq = x0 + 3 * adv;  // next load target: t=3

  FragU hb, h2b;
  hb.q  = (uint32x4){0u, 0u, 0u, 0u};  // h1_{-1}
  h2b.q = (uint32x4){0u, 0u, 0u, 0u};  // h2_{-1}
  float c1[4] = {0.f, 0.f, 0.f, 0.f};
  float c2[4] = {0.f, 0.f, 0.f, 0.f};
  float h2v[4] = {0.f, 0.f, 0.f, 0.f};

  FragU xch, xcl;
  cvt(rw0, xch, xcl);  // x(0)

  // ga = L1 gate preacts for t=0. hb = 0 -> h-part is exactly zero; the
  // x-part 3-chain alone is bit-identical to R6's 5-chain with zero B.
  f32x4 ga[4];
#pragma unroll
  for (int tn = 0; tn < 4; ++tn) {
    f32x4 acc = MFMA16(A1h[tn].v, xch.v, bias1v[tn]);
    acc = MFMA16(A1l[tn].v, xch.v, acc);
    acc = MFMA16(A1h[tn].v, xcl.v, acc);
    ga[tn] = acc;
  }
  cvt(rw1, xch, xcl);  // x(1) ready for the loop's early x-part MFMAs

#pragma unroll 2
  for (int t = 0; t < 100; ++t) {
    // ---- (0) early MFMA chains with no fresh dependencies ----
    // x-part of L1 gates for t+1 (xch = x(t+1), converted last iteration):
    f32x4 gx[4];
#pragma unroll
    for (int tn = 0; tn < 4; ++tn) {
      f32x4 acc = MFMA16(A1h[tn].v, xch.v, bias1v[tn]);
      acc = MFMA16(A1l[tn].v, xch.v, acc);
      acc = MFMA16(A1h[tn].v, xcl.v, acc);
      gx[tn] = acc;
    }
    // h2-part of L2 gates for t (h2b = h2(t-1), from last iteration's ew):
    f32x4 q2[4];
#pragma unroll
    for (int tn = 0; tn < 4; ++tn) {
      f32x4 acc = MFMA16(A4h[tn].v, h2b.v, bias2v[tn]);
      acc = MFMA16(A4l[tn].v, h2b.v, acc);
      q2[tn] = acc;
    }

    // ---- (1) L1 elementwise (t): ga -> h1(t) as packed hi/lo ----
    // MFMA latency of (0) drains under these ~160cy of transcendentals.
    FragU rb;
#pragma unroll
    for (int r = 0; r < 4; ++r) {
      const float iv = sigm(ga[0][r]);
      const float fv = sigm(ga[1][r]);
      const float gv = tanh_(ga[2][r]);
      const float ov = sigm(ga[3][r]);
      const float cc = fv * c1[r] + iv * gv;
      c1[r] = cc;
      const float h = ov * tanh_(cc);
      const unsigned int pk = split_pack(h);
      hb.d[r] = pk;
      rb.d[r] = (h > 0.f) ? pk : 0u;  // relu: identical split when positive
    }

    // ---- (2) L2 rb-part (2-deep) + combine: gb = q2 + A3*rb ----
    f32x4 gb[4];
#pragma unroll
    for (int tn = 0; tn < 4; ++tn) {
      f32x4 acc = MFMA16(A3h[tn].v, rb.v, z4);
      acc = MFMA16(A3l[tn].v, rb.v, acc);
      gb[tn] = q2[tn] + acc;
    }

    // ---- (3) L1 hb-part (2-deep) + combine: ga_next = gx + A2*hb ----
    f32x4 gan[4];
#pragma unroll
    for (int tn = 0; tn < 4; ++tn) {
      f32x4 acc = MFMA16(A2h[tn].v, hb.v, z4);
      acc = MFMA16(A2l[tn].v, hb.v, acc);
      gan[tn] = gx[tn] + acc;
    }

    // ---- (4) convert x(t+2) from raw regs (loaded 2 iters ago) ----
    FragU nxh, nxl;
    cvt(rw, nxh, nxl);

    // ---- (5) issue raw load x(t+3); uniform guard past the end ----
    RawX rwn = loadraw((t <= 96) ? xq : x0);
    xq += adv;

    // ---- (6) L2 elementwise (t): gb latency hidden by (3)..(5) ----
#pragma unroll
    for (int r = 0; r < 4; ++r) {
      const float iv = sigm(gb[0][r]);
      const float fv = sigm(gb[1][r]);
      const float gv = tanh_(gb[2][r]);
      const float ov = sigm(gb[3][r]);
      const float cc = fv * c2[r] + iv * gv;
      c2[r] = cc;
      const float h = ov * tanh_(cc);
      h2v[r] = h;
      h2b.d[r] = split_pack(h);
    }

    // rotate pipeline registers (elided by unroll-2 ping-pong)
#pragma unroll
    for (int tn = 0; tn < 4; ++tn) ga[tn] = gan[tn];
    xch = nxh;
    xcl = nxl;
    rw = rwn;
  }

  // ---- output: relu(h2_last); lane (b,g) holds units 4g..4g+3 of batch b ----
  f32x4 o;
#pragma unroll
  for (int r = 0; r < 4; ++r) o[r] = fmaxf(h2v[r], 0.f);
  *(f32x4*)(out + (size_t)(b0 + b) * 16 + 4 * g) = o;  // 16B-aligned

  (void)x0;
}

extern "C" void kernel_launch(void* const* d_in, const int* in_sizes, int n_in,
                              void* d_out, int out_size, void* d_ws, size_t ws_size,
                              hipStream_t stream) {
  (void)in_sizes; (void)n_in; (void)d_ws; (void)ws_size; (void)out_size;
  // 16384 batch / 16 per wave / 4 waves per block = 256 blocks (1 per CU).
  enc_kernel<<<dim3(256), dim3(256), 0, stream>>>(
      (const float*)d_in[0],
      (const float*)d_in[1],
      (const float*)d_in[2],
      (const float*)d_in[3],
      (const float*)d_in[4],
      (const float*)d_in[5],
      (const float*)d_in[6],
      (const float*)d_in[7],
      (const float*)d_in[8],
      (float*)d_out);
}

// Round 3
// 301.490 us; speedup vs baseline: 1.0115x; 1.0115x over previous
//
#include <hip/hip_runtime.h>

// Encoder: 2-layer LSTM (H=16 each), x [B=16384, T=100, I=18], FP32 in/out.
// R9: tile-8 batch duplication + r-split elementwise. R6 (141.6us) ran
// 1 wave/SIMD: MFMA pipe (36 x ~19.4cy/SIMD = 700cy) and VALU (1730cy)
// SERIALIZE through a lone wave + ~970cy of un-fillable bubbles. R7 proved
// barrier-synced splitting loses; R8 proved chain-splitting loses (MFMA
// result-read stalls + acc pressure). R9 adds waves WITHOUT sync:
//   - 8 batches per wave -> 2048 waves = 2/SIMD, fully independent.
//   - B-fragment duplicates batch columns (cols 8..15 == cols 0..7), so
//     lane (g,b) and partner (g,b^8) hold BIT-IDENTICAL gate preacts.
//   - Elementwise is split by C-row: lane b<8 updates cells r=0,1
//     (units 4g,4g+1), lane b>=8 updates r=2,3 -> per-wave ew HALVES.
//   - Next B-fragment reassembled with 2 shfl_xor(8) + 4 cndmask per
//     frag (hb, rb, h2b) -- partner already holds the other half.
// Per-SIMD: VALU 2x~1420, MFMA 2x700, overlapped across 2 waves (m114);
// the pair mutually fills R6's single-wave stalls.
// Numerics: BIT-EXACT vs R6 (identical MFMA inputs, identical ew ops;
// exchange moves exact bits; perm packing proven bit-exact in R8).
// Pipeline per iteration t (R6's proven order):
//   L1-ew(t)+exchange -> L2-MFMAs(t) -> L1-MFMAs(t+1) -> x-convert(t+2) ->
//   raw-load(t+3) -> L2-ew(t)+exchange

typedef float f32x4 __attribute__((ext_vector_type(4)));
typedef __bf16 bf16x8 __attribute__((ext_vector_type(8)));
typedef unsigned int uint32x4 __attribute__((ext_vector_type(4)));

union FragU { bf16x8 v; unsigned short u[8]; unsigned int d[4]; uint32x4 q; };

#define MFMA16(A, B, C) __builtin_amdgcn_mfma_f32_16x16x32_bf16((A), (B), (C), 0, 0, 0)

static __device__ __forceinline__ unsigned short f2bf(float f) {  // RNE (weights)
  unsigned int u = __builtin_bit_cast(unsigned int, f);
  u = u + 0x7FFFu + ((u >> 16) & 1u);
  return (unsigned short)(u >> 16);
}
static __device__ __forceinline__ float bfbits2f(unsigned short h) {
  unsigned int u = ((unsigned int)h) << 16;
  return __builtin_bit_cast(float, u);
}
static __device__ __forceinline__ float sigm(float x) {
  // 1/(1+exp(-x)); saturates cleanly, never NaN for finite x.
  return __builtin_amdgcn_rcpf(1.0f + __builtin_amdgcn_exp2f(x * -1.4426950408889634f));
}
static __device__ __forceinline__ float tanh_(float x) {
  // 1 - 2/(1+exp(2x)); saturates to +-1.
  return 1.0f - 2.0f * __builtin_amdgcn_rcpf(1.0f + __builtin_amdgcn_exp2f(x * 2.8853900817779268f));
}
// Trunc two-term split packed as (bf_hi | bf_lo<<16), via v_perm_b32:
// D bytes {l[3],l[2],u[3],u[2]} == (u>>16) | (l & 0xFFFF0000). Bit-exact
// vs the shift/or form (R8 absmax identical).
static __device__ __forceinline__ unsigned int split_pack(float v) {
  unsigned int u = __builtin_bit_cast(unsigned int, v);
  float hf = __builtin_bit_cast(float, u & 0xFFFF0000u);
  unsigned int l = __builtin_bit_cast(unsigned int, v - hf);
  return __builtin_amdgcn_perm(l, u, 0x07060302u);
}
// Split a float pair into hi-frag dword and lo-frag dword (6 VALU via perm).
static __device__ __forceinline__ void cvt_pair(float f0, float f1,
                                                unsigned int& hd, unsigned int& ld) {
  unsigned int u0 = __builtin_bit_cast(unsigned int, f0);
  unsigned int u1 = __builtin_bit_cast(unsigned int, f1);
  unsigned int h0 = u0 & 0xFFFF0000u;
  unsigned int h1 = u1 & 0xFFFF0000u;
  hd = __builtin_amdgcn_perm(u1, u0, 0x07060302u);
  unsigned int l0 = __builtin_bit_cast(unsigned int, f0 - __builtin_bit_cast(float, h0));
  unsigned int l1 = __builtin_bit_cast(unsigned int, f1 - __builtin_bit_cast(float, h1));
  ld = __builtin_amdgcn_perm(l1, l0, 0x07060302u);
}

struct RawX { float2 a, b2, c, d; };

__global__ __launch_bounds__(256, 2) void enc_kernel(
    const float* __restrict__ x,     // [16384,100,18]
    const float* __restrict__ Wih1,  // [64,18]
    const float* __restrict__ Whh1,  // [64,16]
    const float* __restrict__ bih1,  // [64]
    const float* __restrict__ bhh1,  // [64]
    const float* __restrict__ Wih2,  // [64,16]
    const float* __restrict__ Whh2,  // [64,16]
    const float* __restrict__ bih2,  // [64]
    const float* __restrict__ bhh2,  // [64]
    float* __restrict__ out)         // [16384,16]
{
  const int lane = threadIdx.x & 63;
  const int b    = lane & 15;  // B n-col; batch = b0 + (b&7), cols 8..15 dup
  const int g    = lane >> 4;  // k-group; C row-quad (units 4g..4g+3)
  const bool lo  = (b < 8);    // this lane's ew half: rows 4g+{0,1} vs {2,3}

  const int wid = (int)((blockIdx.x * blockDim.x + threadIdx.x) >> 6);
  const int b0  = wid * 8;     // 8 batches per wave

  // ---- loop-invariant weight A-fragments: A[m=lane&15][k=8g+j] ----
  FragU A1h[4], A1l[4], A2h[4], A2l[4], A3h[4], A3l[4], A4h[4], A4l[4];
  f32x4 bias1v[4], bias2v[4];
#pragma unroll
  for (int tn = 0; tn < 4; ++tn) {  // 0=i 1=f 2=g 3=o (PyTorch gate order)
    const int row = tn * 16 + b;
#pragma unroll
    for (int j = 0; j < 8; ++j) {
      const int k = 8 * g + j;
      if (k < 18) {
        const float w = Wih1[row * 18 + k];
        A1h[tn].u[j] = f2bf(w);
        A1l[tn].u[j] = f2bf(w - bfbits2f(A1h[tn].u[j]));
      } else {
        A1h[tn].u[j] = 0;
        A1l[tn].u[j] = 0;
      }
      const int kk = k >> 1;  // hi/lo interleave: both K slots share the weight
      const float w2 = Whh1[row * 16 + kk];
      const float w3 = Wih2[row * 16 + kk];
      const float w4 = Whh2[row * 16 + kk];
      A2h[tn].u[j] = f2bf(w2); A2l[tn].u[j] = f2bf(w2 - bfbits2f(A2h[tn].u[j]));
      A3h[tn].u[j] = f2bf(w3); A3l[tn].u[j] = f2bf(w3 - bfbits2f(A3h[tn].u[j]));
      A4h[tn].u[j] = f2bf(w4); A4l[tn].u[j] = f2bf(w4 - bfbits2f(A4h[tn].u[j]));
    }
#pragma unroll
    for (int r = 0; r < 4; ++r) {
      const int u4 = tn * 16 + 4 * g + r;  // C row = unit 4g+r of gate tn
      bias1v[tn][r] = bih1[u4] + bhh1[u4];
      bias2v[tn][r] = bih2[u4] + bhh2[u4];
    }
  }

  // ---- x addressing: lane (b,g) covers x[b0+(b&7)][t][8g .. 8g+7] ----
  // Partner lanes (b^8) load identical addresses -> coalescer merges.
  // g==3 lanes: k=24..31 all beyond I=18; B-slots multiply zero weights.
  const float* const x0 = x + (size_t)(b0 + (b & 7)) * 1800 + 8 * g;
  const int adv = (g == 3) ? 0 : 18;

  auto loadraw = [&](const float* p) -> RawX {
    RawX r;
    r.a = *(const float2*)p;  // g<2: k 8g..8g+1; g==2: k 16,17; g==3: dummy
    if (g < 2) {              // full 8 features, in-bounds for all t
      r.b2 = *(const float2*)(p + 2);
      r.c  = *(const float2*)(p + 4);
      r.d  = *(const float2*)(p + 6);
    } else {                  // g>=2: only pair a matters (k>=18 hits A-pad)
      r.b2 = r.c = r.d = make_float2(0.f, 0.f);
    }
    return r;
  };
  auto cvt = [&](const RawX& rw_, FragU& hi, FragU& lo_) {
    cvt_pair(rw_.a.x, rw_.a.y, hi.d[0], lo_.d[0]);
    cvt_pair(rw_.b2.x, rw_.b2.y, hi.d[1], lo_.d[1]);
    cvt_pair(rw_.c.x, rw_.c.y, hi.d[2], lo_.d[2]);
    cvt_pair(rw_.d.x, rw_.d.y, hi.d[3], lo_.d[3]);
  };

  // ---- prologue: raw x for t=0,1,2 in flight together ----
  RawX rw0 = loadraw(x0);
  RawX rw1 = loadraw(x0 + adv);
  RawX rw  = loadraw(x0 + 2 * adv);
  const float* xq = x0 + 3 * adv;  // next load target: t=3

  FragU hb, h2b;
  hb.q  = (uint32x4){0u, 0u, 0u, 0u};  // h1_{-1}
  h2b.q = (uint32x4){0u, 0u, 0u, 0u};  // h2_{-1}
  float c1s0 = 0.f, c1s1 = 0.f;        // L1 c-state, this lane's 2 units
  float c2s0 = 0.f, c2s1 = 0.f;        // L2 c-state
  float h2o0 = 0.f, h2o1 = 0.f;        // last h2 (for output)

  FragU xch, xcl;
  cvt(rw0, xch, xcl);  // x(0)

  // ga = L1 gate preacts for t=0 (hb = 0); R6's exact 5-chain
  f32x4 ga[4];
#pragma unroll
  for (int tn = 0; tn < 4; ++tn) {
    f32x4 acc = MFMA16(A1h[tn].v, xch.v, bias1v[tn]);
    acc = MFMA16(A1l[tn].v, xch.v, acc);
    acc = MFMA16(A1h[tn].v, xcl.v, acc);
    acc = MFMA16(A2h[tn].v, hb.v, acc);
    acc = MFMA16(A2l[tn].v, hb.v, acc);
    ga[tn] = acc;
  }
  cvt(rw1, xch, xcl);  // x(1) ready for the loop's L1-MFMAs(t+1)

#pragma unroll 2
  for (int t = 0; t < 100; ++t) {
    // ---- (1) L1 ew (t): this lane's 2 cells; exchange with partner ----
    {
      const float pi0 = lo ? ga[0][0] : ga[0][2];
      const float pi1 = lo ? ga[0][1] : ga[0][3];
      const float pf0 = lo ? ga[1][0] : ga[1][2];
      const float pf1 = lo ? ga[1][1] : ga[1][3];
      const float pg0 = lo ? ga[2][0] : ga[2][2];
      const float pg1 = lo ? ga[2][1] : ga[2][3];
      const float po0 = lo ? ga[3][0] : ga[3][2];
      const float po1 = lo ? ga[3][1] : ga[3][3];
      const float cc0 = sigm(pf0) * c1s0 + sigm(pi0) * tanh_(pg0);
      const float cc1 = sigm(pf1) * c1s1 + sigm(pi1) * tanh_(pg1);
      c1s0 = cc0; c1s1 = cc1;
      const float h0 = sigm(po0) * tanh_(cc0);
      const float h1 = sigm(po1) * tanh_(cc1);
      const unsigned int pk0 = split_pack(h0);
      const unsigned int pk1 = split_pack(h1);
      const unsigned int rk0 = (h0 > 0.f) ? pk0 : 0u;  // relu'd copy
      const unsigned int rk1 = (h1 > 0.f) ? pk1 : 0u;
      // partner (lane^8) holds the other row-pair of the SAME batch
      const unsigned int qp0 = (unsigned int)__shfl_xor((int)pk0, 8, 64);
      const unsigned int qp1 = (unsigned int)__shfl_xor((int)pk1, 8, 64);
      const unsigned int qr0 = (unsigned int)__shfl_xor((int)rk0, 8, 64);
      const unsigned int qr1 = (unsigned int)__shfl_xor((int)rk1, 8, 64);
      hb.d[0] = lo ? pk0 : qp0;  hb.d[1] = lo ? pk1 : qp1;
      hb.d[2] = lo ? qp0 : pk0;  hb.d[3] = lo ? qp1 : pk1;
      FragU rb;
      rb.d[0] = lo ? rk0 : qr0;  rb.d[1] = lo ? rk1 : qr1;
      rb.d[2] = lo ? qr0 : rk0;  rb.d[3] = lo ? qr1 : rk1;

      // ---- (2) L2 MFMAs (t): uses rb (fresh) and h2b = h2(t-1) ----
      f32x4 gb[4];
#pragma unroll
      for (int tn = 0; tn < 4; ++tn) {
        f32x4 acc = MFMA16(A4h[tn].v, h2b.v, bias2v[tn]);
        acc = MFMA16(A4l[tn].v, h2b.v, acc);
        acc = MFMA16(A3h[tn].v, rb.v, acc);
        acc = MFMA16(A3l[tn].v, rb.v, acc);
        gb[tn] = acc;
      }

      // ---- (3) L1 MFMAs (t+1): independent of gb; hides MFMA latency ----
      f32x4 gan[4];
#pragma unroll
      for (int tn = 0; tn < 4; ++tn) {
        f32x4 acc = MFMA16(A1h[tn].v, xch.v, bias1v[tn]);
        acc = MFMA16(A1l[tn].v, xch.v, acc);
        acc = MFMA16(A1h[tn].v, xcl.v, acc);
        acc = MFMA16(A2h[tn].v, hb.v, acc);
        acc = MFMA16(A2l[tn].v, hb.v, acc);
        gan[tn] = acc;
      }

      // ---- (4) convert x(t+2) from raw regs (loaded 2 iters ago) ----
      FragU nxh, nxl;
      cvt(rw, nxh, nxl);

      // ---- (5) issue raw load x(t+3); uniform guard past the end ----
      RawX rwn = loadraw((t <= 96) ? xq : x0);
      xq += adv;

      // ---- (6) L2 ew (t): gb arrived long ago; exchange h2 ----
      const float qi0 = lo ? gb[0][0] : gb[0][2];
      const float qi1 = lo ? gb[0][1] : gb[0][3];
      const float qf0 = lo ? gb[1][0] : gb[1][2];
      const float qf1 = lo ? gb[1][1] : gb[1][3];
      const float qg0 = lo ? gb[2][0] : gb[2][2];
      const float qg1 = lo ? gb[2][1] : gb[2][3];
      const float qo0 = lo ? gb[3][0] : gb[3][2];
      const float qo1 = lo ? gb[3][1] : gb[3][3];
      const float dd0 = sigm(qf0) * c2s0 + sigm(qi0) * tanh_(qg0);
      const float dd1 = sigm(qf1) * c2s1 + sigm(qi1) * tanh_(qg1);
      c2s0 = dd0; c2s1 = dd1;
      const float g0 = sigm(qo0) * tanh_(dd0);
      const float g1 = sigm(qo1) * tanh_(dd1);
      h2o0 = g0; h2o1 = g1;
      const unsigned int hk0 = split_pack(g0);
      const unsigned int hk1 = split_pack(g1);
      const unsigned int qh0 = (unsigned int)__shfl_xor((int)hk0, 8, 64);
      const unsigned int qh1 = (unsigned int)__shfl_xor((int)hk1, 8, 64);
      h2b.d[0] = lo ? hk0 : qh0;  h2b.d[1] = lo ? hk1 : qh1;
      h2b.d[2] = lo ? qh0 : hk0;  h2b.d[3] = lo ? qh1 : hk1;

      // rotate pipeline registers (elided by unroll-2 ping-pong)
#pragma unroll
      for (int tn = 0; tn < 4; ++tn) ga[tn] = gan[tn];
      xch = nxh;
      xcl = nxl;
      rw = rwn;
    }
  }

  // ---- output: relu(h2_last); lane (g,b) holds units 4g+(lo?0:2)+{0,1} ----
  float2 o;
  o.x = fmaxf(h2o0, 0.f);
  o.y = fmaxf(h2o1, 0.f);
  *(float2*)(out + (size_t)(b0 + (b & 7)) * 16 + 4 * g + (lo ? 0 : 2)) = o;

  (void)x0;
}

extern "C" void kernel_launch(void* const* d_in, const int* in_sizes, int n_in,
                              void* d_out, int out_size, void* d_ws, size_t ws_size,
                              hipStream_t stream) {
  (void)in_sizes; (void)n_in; (void)d_ws; (void)ws_size; (void)out_size;
  // 16384 batch / 8 per wave / 4 waves per block = 512 blocks (2 per CU)
  // -> 8 waves/CU = 2 waves/SIMD, no inter-wave sync.
  enc_kernel<<<dim3(512), dim3(256), 0, stream>>>(
      (const float*)d_in[0],
      (const float*)d_in[1],
      (const float*)d_in[2],
      (const float*)d_in[3],
      (const float*)d_in[4],
      (const float*)d_in[5],
      (const float*)d_in[6],
      (const float*)d_in[7],
      (const float*)d_in[8],
      (float*)d_out);
}

// Round 4
// 292.006 us; speedup vs baseline: 1.0444x; 1.0325x over previous
//
#include <hip/hip_runtime.h>

// Encoder: 2-layer LSTM (H=16 each), x [B=16384, T=100, I=18], FP32 in/out.
// R10: R6 structure (best measured: 141.6us; tile-16, 1 wave/SIMD) with ONE
// bit-exact change: the L2(t) and L1(t+1) MFMA chains are emitted DEPTH-MAJOR
// (all 8 independent chains interleaved: for depth { for chain }) instead of
// tn-major (for chain { for depth }). R6's tn-major order put 4-5 dependent
// MFMAs back-to-back in program order; an in-order wave stalls at each
// dependent MFMA for (latency - issue) with independent work trapped behind
// it. Evidence: R6 dead time ~1600cy/iter; R9 showed a second independent
// wave does NOT fill it (stall is positional, not generic); R8 (chains split
// + immediate MFMA->VALU reads) made it worse. Depth-major puts 8 MFMA
// issues (~155cy) between dependent pairs >> result latency -> no stall.
// Per-chain accumulation order is UNCHANGED -> bit-identical numerics.
// One wave per 16-batch tile (1024 waves, structural). G^T = W @ H^T:
// C/D col=lane&15=batch, row=quad*4+reg=unit; packed (hi|lo<<16) h dwords
// ARE the next step's B-fragment -> recurrence never leaves registers.
// Pipeline per iteration t:
//   L1-ew(t) -> [L2(t) + L1(t+1) MFMAs, depth-major] -> x-convert(t+2) ->
//   raw-load(t+3) -> L2-ew(t)
// PRECISION: identical two-term trunc splits to R6 (measured 9.77e-4 vs
// 3.9e-3 threshold); v_perm packing proven bit-exact in R8/R9.

typedef float f32x4 __attribute__((ext_vector_type(4)));
typedef __bf16 bf16x8 __attribute__((ext_vector_type(8)));
typedef unsigned int uint32x4 __attribute__((ext_vector_type(4)));

union FragU { bf16x8 v; unsigned short u[8]; unsigned int d[4]; uint32x4 q; };

#define MFMA16(A, B, C) __builtin_amdgcn_mfma_f32_16x16x32_bf16((A), (B), (C), 0, 0, 0)

static __device__ __forceinline__ unsigned short f2bf(float f) {  // RNE (weights)
  unsigned int u = __builtin_bit_cast(unsigned int, f);
  u = u + 0x7FFFu + ((u >> 16) & 1u);
  return (unsigned short)(u >> 16);
}
static __device__ __forceinline__ float bfbits2f(unsigned short h) {
  unsigned int u = ((unsigned int)h) << 16;
  return __builtin_bit_cast(float, u);
}
static __device__ __forceinline__ float sigm(float x) {
  // 1/(1+exp(-x)); saturates cleanly, never NaN for finite x.
  return __builtin_amdgcn_rcpf(1.0f + __builtin_amdgcn_exp2f(x * -1.4426950408889634f));
}
static __device__ __forceinline__ float tanh_(float x) {
  // 1 - 2/(1+exp(2x)); saturates to +-1.
  return 1.0f - 2.0f * __builtin_amdgcn_rcpf(1.0f + __builtin_amdgcn_exp2f(x * 2.8853900817779268f));
}
// Trunc two-term split packed as (bf_hi | bf_lo<<16), via v_perm_b32:
// D bytes {l[3],l[2],u[3],u[2]} == (u>>16) | (l & 0xFFFF0000). Bit-exact.
static __device__ __forceinline__ unsigned int split_pack(float v) {
  unsigned int u = __builtin_bit_cast(unsigned int, v);
  float hf = __builtin_bit_cast(float, u & 0xFFFF0000u);
  unsigned int l = __builtin_bit_cast(unsigned int, v - hf);
  return __builtin_amdgcn_perm(l, u, 0x07060302u);
}
// Split a float pair into hi-frag dword and lo-frag dword (6 VALU via perm).
static __device__ __forceinline__ void cvt_pair(float f0, float f1,
                                                unsigned int& hd, unsigned int& ld) {
  unsigned int u0 = __builtin_bit_cast(unsigned int, f0);
  unsigned int u1 = __builtin_bit_cast(unsigned int, f1);
  unsigned int h0 = u0 & 0xFFFF0000u;
  unsigned int h1 = u1 & 0xFFFF0000u;
  hd = __builtin_amdgcn_perm(u1, u0, 0x07060302u);
  unsigned int l0 = __builtin_bit_cast(unsigned int, f0 - __builtin_bit_cast(float, h0));
  unsigned int l1 = __builtin_bit_cast(unsigned int, f1 - __builtin_bit_cast(float, h1));
  ld = __builtin_amdgcn_perm(l1, l0, 0x07060302u);
}

struct RawX { float2 a, b2, c, d; };

__global__ __launch_bounds__(256, 1) void enc_kernel(
    const float* __restrict__ x,     // [16384,100,18]
    const float* __restrict__ Wih1,  // [64,18]
    const float* __restrict__ Whh1,  // [64,16]
    const float* __restrict__ bih1,  // [64]
    const float* __restrict__ bhh1,  // [64]
    const float* __restrict__ Wih2,  // [64,16]
    const float* __restrict__ Whh2,  // [64,16]
    const float* __restrict__ bih2,  // [64]
    const float* __restrict__ bhh2,  // [64]
    float* __restrict__ out)         // [16384,16]
{
  const int lane = threadIdx.x & 63;
  const int b    = lane & 15;  // batch in tile: A m-row / B n-col / C col
  const int g    = lane >> 4;  // k-group; C row-quad (units 4g..4g+3)

  const int wid = (int)((blockIdx.x * blockDim.x + threadIdx.x) >> 6);
  const int b0  = wid * 16;

  // ---- loop-invariant weight A-fragments: A[m=lane&15][k=8g+j] ----
  FragU A1h[4], A1l[4], A2h[4], A2l[4], A3h[4], A3l[4], A4h[4], A4l[4];
  f32x4 bias1v[4], bias2v[4];
#pragma unroll
  for (int tn = 0; tn < 4; ++tn) {  // 0=i 1=f 2=g 3=o (PyTorch gate order)
    const int row = tn * 16 + b;
#pragma unroll
    for (int j = 0; j < 8; ++j) {
      const int k = 8 * g + j;
      if (k < 18) {
        const float w = Wih1[row * 18 + k];
        A1h[tn].u[j] = f2bf(w);
        A1l[tn].u[j] = f2bf(w - bfbits2f(A1h[tn].u[j]));
      } else {
        A1h[tn].u[j] = 0;
        A1l[tn].u[j] = 0;
      }
      const int kk = k >> 1;  // hi/lo interleave: both K slots share the weight
      const float w2 = Whh1[row * 16 + kk];
      const float w3 = Wih2[row * 16 + kk];
      const float w4 = Whh2[row * 16 + kk];
      A2h[tn].u[j] = f2bf(w2); A2l[tn].u[j] = f2bf(w2 - bfbits2f(A2h[tn].u[j]));
      A3h[tn].u[j] = f2bf(w3); A3l[tn].u[j] = f2bf(w3 - bfbits2f(A3h[tn].u[j]));
      A4h[tn].u[j] = f2bf(w4); A4l[tn].u[j] = f2bf(w4 - bfbits2f(A4h[tn].u[j]));
    }
#pragma unroll
    for (int r = 0; r < 4; ++r) {
      const int u4 = tn * 16 + 4 * g + r;  // C row = unit 4g+r of gate tn
      bias1v[tn][r] = bih1[u4] + bhh1[u4];
      bias2v[tn][r] = bih2[u4] + bhh2[u4];
    }
  }

  // ---- x addressing: lane (b,g) covers x[b0+b][t][8g .. 8g+7] ----
  // g==3 lanes: k=24..31 are all beyond I=18; their B-slots multiply zero
  // weights (A1 pad), so they read a fixed valid address and never advance.
  const float* const x0 = x + (size_t)(b0 + b) * 1800 + 8 * g;
  const int adv = (g == 3) ? 0 : 18;

  auto loadraw = [&](const float* p) -> RawX {
    RawX r;
    r.a = *(const float2*)p;  // g<2: k 8g..8g+1; g==2: k 16,17; g==3: dummy
    if (g < 2) {              // full 8 features, in-bounds for all t
      r.b2 = *(const float2*)(p + 2);
      r.c  = *(const float2*)(p + 4);
      r.d  = *(const float2*)(p + 6);
    } else {                  // g>=2: only pair a matters (k>=18 hits A-pad)
      r.b2 = r.c = r.d = make_float2(0.f, 0.f);
    }
    return r;
  };
  auto cvt = [&](const RawX& rw_, FragU& hi, FragU& lo) {
    cvt_pair(rw_.a.x, rw_.a.y, hi.d[0], lo.d[0]);
    cvt_pair(rw_.b2.x, rw_.b2.y, hi.d[1], lo.d[1]);
    cvt_pair(rw_.c.x, rw_.c.y, hi.d[2], lo.d[2]);
    cvt_pair(rw_.d.x, rw_.d.y, hi.d[3], lo.d[3]);
  };

  // ---- prologue: raw x for t=0,1,2 in flight together ----
  RawX rw0 = loadraw(x0);
  RawX rw1 = loadraw(x0 + adv);
  RawX rw  = loadraw(x0 + 2 * adv);
  const float* xq = x0 + 3 * adv;  // next load target: t=3

  FragU hb, h2b;
  hb.q  = (uint32x4){0u, 0u, 0u, 0u};  // h1_{-1}
  h2b.q = (uint32x4){0u, 0u, 0u, 0u};  // h2_{-1}
  float c1[4] = {0.f, 0.f, 0.f, 0.f};
  float c2[4] = {0.f, 0.f, 0.f, 0.f};
  float h2v[4] = {0.f, 0.f, 0.f, 0.f};

  FragU xch, xcl;
  cvt(rw0, xch, xcl);  // x(0)

  // ga = L1 gate preacts for t=0 (hb = 0); R6's exact 5-chain, depth-major
  f32x4 ga[4];
#pragma unroll
  for (int tn = 0; tn < 4; ++tn) ga[tn] = MFMA16(A1h[tn].v, xch.v, bias1v[tn]);
#pragma unroll
  for (int tn = 0; tn < 4; ++tn) ga[tn] = MFMA16(A1l[tn].v, xch.v, ga[tn]);
#pragma unroll
  for (int tn = 0; tn < 4; ++tn) ga[tn] = MFMA16(A1h[tn].v, xcl.v, ga[tn]);
#pragma unroll
  for (int tn = 0; tn < 4; ++tn) ga[tn] = MFMA16(A2h[tn].v, hb.v, ga[tn]);
#pragma unroll
  for (int tn = 0; tn < 4; ++tn) ga[tn] = MFMA16(A2l[tn].v, hb.v, ga[tn]);
  cvt(rw1, xch, xcl);  // x(1) ready for the loop's L1-MFMAs(t+1)

#pragma unroll 2
  for (int t = 0; t < 100; ++t) {
    // ---- (1) L1 elementwise (t): ga -> h1(t) as packed hi/lo ----
    FragU rb;
#pragma unroll
    for (int r = 0; r < 4; ++r) {
      const float iv = sigm(ga[0][r]);
      const float fv = sigm(ga[1][r]);
      const float gv = tanh_(ga[2][r]);
      const float ov = sigm(ga[3][r]);
      const float cc = fv * c1[r] + iv * gv;
      c1[r] = cc;
      const float h = ov * tanh_(cc);
      const unsigned int pk = split_pack(h);
      hb.d[r] = pk;
      rb.d[r] = (h > 0.f) ? pk : 0u;  // relu: identical split when positive
    }

    // ---- (2) L2(t) + L1(t+1) MFMAs, DEPTH-MAJOR across all 8 chains ----
    // Chain orders identical to R6:
    //   gb[tn] : A4h*h2b -> A4l*h2b -> A3h*rb -> A3l*rb      (bias2 seed)
    //   gan[tn]: A1h*xch -> A1l*xch -> A1h*xcl -> A2h*hb -> A2l*hb (bias1 seed)
    // Program order interleaves 8 independent MFMAs between dependent pairs.
    f32x4 gb[4], gan[4];
#pragma unroll
    for (int tn = 0; tn < 4; ++tn) gb[tn]  = MFMA16(A4h[tn].v, h2b.v, bias2v[tn]);
#pragma unroll
    for (int tn = 0; tn < 4; ++tn) gan[tn] = MFMA16(A1h[tn].v, xch.v, bias1v[tn]);
#pragma unroll
    for (int tn = 0; tn < 4; ++tn) gb[tn]  = MFMA16(A4l[tn].v, h2b.v, gb[tn]);
#pragma unroll
    for (int tn = 0; tn < 4; ++tn) gan[tn] = MFMA16(A1l[tn].v, xch.v, gan[tn]);
#pragma unroll
    for (int tn = 0; tn < 4; ++tn) gb[tn]  = MFMA16(A3h[tn].v, rb.v, gb[tn]);
#pragma unroll
    for (int tn = 0; tn < 4; ++tn) gan[tn] = MFMA16(A1h[tn].v, xcl.v, gan[tn]);
#pragma unroll
    for (int tn = 0; tn < 4; ++tn) gb[tn]  = MFMA16(A3l[tn].v, rb.v, gb[tn]);
#pragma unroll
    for (int tn = 0; tn < 4; ++tn) gan[tn] = MFMA16(A2h[tn].v, hb.v, gan[tn]);
#pragma unroll
    for (int tn = 0; tn < 4; ++tn) gan[tn] = MFMA16(A2l[tn].v, hb.v, gan[tn]);

    // ---- (4) convert x(t+2) from raw regs (loaded 2 iters ago) ----
    FragU nxh, nxl;
    cvt(rw, nxh, nxl);

    // ---- (5) issue raw load x(t+3); uniform guard past the end ----
    RawX rwn = loadraw((t <= 96) ? xq : x0);
    xq += adv;

    // ---- (6) L2 elementwise (t): gb latency drained under (4)/(5) ----
#pragma unroll
    for (int r = 0; r < 4; ++r) {
      const float iv = sigm(gb[0][r]);
      const float fv = sigm(gb[1][r]);
      const float gv = tanh_(gb[2][r]);
      const float ov = sigm(gb[3][r]);
      const float cc = fv * c2[r] + iv * gv;
      c2[r] = cc;
      const float h = ov * tanh_(cc);
      h2v[r] = h;
      h2b.d[r] = split_pack(h);
    }

    // rotate pipeline registers (elided by unroll-2 ping-pong)
#pragma unroll
    for (int tn = 0; tn < 4; ++tn) ga[tn] = gan[tn];
    xch = nxh;
    xcl = nxl;
    rw = rwn;
  }

  // ---- output: relu(h2_last); lane (b,g) holds units 4g..4g+3 of batch b ----
  f32x4 o;
#pragma unroll
  for (int r = 0; r < 4; ++r) o[r] = fmaxf(h2v[r], 0.f);
  *(f32x4*)(out + (size_t)(b0 + b) * 16 + 4 * g) = o;  // 16B-aligned

  (void)x0;
}

extern "C" void kernel_launch(void* const* d_in, const int* in_sizes, int n_in,
                              void* d_out, int out_size, void* d_ws, size_t ws_size,
                              hipStream_t stream) {
  (void)in_sizes; (void)n_in; (void)d_ws; (void)ws_size; (void)out_size;
  // 16384 batch / 16 per wave / 4 waves per block = 256 blocks (1 per CU).
  enc_kernel<<<dim3(256), dim3(256), 0, stream>>>(
      (const float*)d_in[0],
      (const float*)d_in[1],
      (const float*)d_in[2],
      (const float*)d_in[3],
      (const float*)d_in[4],
      (const float*)d_in[5],
      (const float*)d_in[6],
      (const float*)d_in[7],
      (const float*)d_in[8],
      (float*)d_out);
}

// Round 5
// 273.056 us; speedup vs baseline: 1.1168x; 1.0694x over previous
//
#include <hip/hip_runtime.h>

// Encoder: 2-layer LSTM (H=16 each), x [B=16384, T=100, I=18], FP32 in/out.
// R11: R6 structure (best measured 141.6us) with ONE pipeline change:
// L2-elementwise is DEFERRED one iteration. R6's body was strictly
//   L1ew(t) -> MFMAs -> L2ew(t)   (L2ew depends on rb(t) via gb(t))
// i.e. two ~4-cell transcendental latency blocks SERIALIZED per iteration,
// plus the MFMA chain between them: ~2xL_ew + MFMA = the ~3400cy/iter wall.
// Evidence: R7 (half work/wave, same per-iter time) => latency-, not
// issue-bound; R9 (2 indep waves) kept the same serial shape per wave and
// didn't help; R10 (MFMA reorder) regressed => MFMA stalls aren't the wall.
// R11's body computes L1ew(t) and L2ew(t-1) SIDE BY SIDE at the loop top
// (8 independent trans cells interleave -> one L_ew instead of two), then
// the MFMA block consumes both fresh outputs (h2b(t-1), rb(t), hb(t)):
//   [L1ew(t) || L2ew(t-1)] -> L2-MFMA(t) -> L1-MFMA(t+1) -> cvt -> load
// gb becomes loop-carried (+16 VGPR); epilogue runs the final L2ew(99).
// t=0's L2ew consumes a dummy gb seeded at -1e3 -> EXACT h2=0, c2=0
// (sigm(-1e3)=rcp(inf)=0; tanh_(0)=1-2*rcp(2)=0).
// All per-value math, operand order, and splits are BIT-IDENTICAL to R6
// (absmax 9.77e-4 vs 3.9e-3 threshold); only the execution phase moves.
// One wave per 16-batch tile (1024 waves, structural). G^T = W @ H^T:
// C/D col=lane&15=batch, row=quad*4+reg=unit; packed (hi|lo<<16) h dwords
// ARE the next step's B-fragment -> recurrence never leaves registers.

typedef float f32x4 __attribute__((ext_vector_type(4)));
typedef __bf16 bf16x8 __attribute__((ext_vector_type(8)));
typedef unsigned int uint32x4 __attribute__((ext_vector_type(4)));

union FragU { bf16x8 v; unsigned short u[8]; unsigned int d[4]; uint32x4 q; };

#define MFMA16(A, B, C) __builtin_amdgcn_mfma_f32_16x16x32_bf16((A), (B), (C), 0, 0, 0)

static __device__ __forceinline__ unsigned short f2bf(float f) {  // RNE (weights)
  unsigned int u = __builtin_bit_cast(unsigned int, f);
  u = u + 0x7FFFu + ((u >> 16) & 1u);
  return (unsigned short)(u >> 16);
}
static __device__ __forceinline__ float bfbits2f(unsigned short h) {
  unsigned int u = ((unsigned int)h) << 16;
  return __builtin_bit_cast(float, u);
}
static __device__ __forceinline__ float sigm(float x) {
  // 1/(1+exp(-x)); saturates cleanly, never NaN for finite x.
  return __builtin_amdgcn_rcpf(1.0f + __builtin_amdgcn_exp2f(x * -1.4426950408889634f));
}
static __device__ __forceinline__ float tanh_(float x) {
  // 1 - 2/(1+exp(2x)); saturates to +-1.
  return 1.0f - 2.0f * __builtin_amdgcn_rcpf(1.0f + __builtin_amdgcn_exp2f(x * 2.8853900817779268f));
}
// Trunc two-term split packed as (bf_hi | bf_lo<<16), via v_perm_b32:
// D bytes {l[3],l[2],u[3],u[2]} == (u>>16) | (l & 0xFFFF0000). Bit-exact.
static __device__ __forceinline__ unsigned int split_pack(float v) {
  unsigned int u = __builtin_bit_cast(unsigned int, v);
  float hf = __builtin_bit_cast(float, u & 0xFFFF0000u);
  unsigned int l = __builtin_bit_cast(unsigned int, v - hf);
  return __builtin_amdgcn_perm(l, u, 0x07060302u);
}
// Split a float pair into hi-frag dword and lo-frag dword (6 VALU via perm).
static __device__ __forceinline__ void cvt_pair(float f0, float f1,
                                                unsigned int& hd, unsigned int& ld) {
  unsigned int u0 = __builtin_bit_cast(unsigned int, f0);
  unsigned int u1 = __builtin_bit_cast(unsigned int, f1);
  unsigned int h0 = u0 & 0xFFFF0000u;
  unsigned int h1 = u1 & 0xFFFF0000u;
  hd = __builtin_amdgcn_perm(u1, u0, 0x07060302u);
  unsigned int l0 = __builtin_bit_cast(unsigned int, f0 - __builtin_bit_cast(float, h0));
  unsigned int l1 = __builtin_bit_cast(unsigned int, f1 - __builtin_bit_cast(float, h1));
  ld = __builtin_amdgcn_perm(l1, l0, 0x07060302u);
}

struct RawX { float2 a, b2, c, d; };

__global__ __launch_bounds__(256, 1) void enc_kernel(
    const float* __restrict__ x,     // [16384,100,18]
    const float* __restrict__ Wih1,  // [64,18]
    const float* __restrict__ Whh1,  // [64,16]
    const float* __restrict__ bih1,  // [64]
    const float* __restrict__ bhh1,  // [64]
    const float* __restrict__ Wih2,  // [64,16]
    const float* __restrict__ Whh2,  // [64,16]
    const float* __restrict__ bih2,  // [64]
    const float* __restrict__ bhh2,  // [64]
    float* __restrict__ out)         // [16384,16]
{
  const int lane = threadIdx.x & 63;
  const int b    = lane & 15;  // batch in tile: A m-row / B n-col / C col
  const int g    = lane >> 4;  // k-group; C row-quad (units 4g..4g+3)

  const int wid = (int)((blockIdx.x * blockDim.x + threadIdx.x) >> 6);
  const int b0  = wid * 16;

  // ---- loop-invariant weight A-fragments: A[m=lane&15][k=8g+j] ----
  FragU A1h[4], A1l[4], A2h[4], A2l[4], A3h[4], A3l[4], A4h[4], A4l[4];
  f32x4 bias1v[4], bias2v[4];
#pragma unroll
  for (int tn = 0; tn < 4; ++tn) {  // 0=i 1=f 2=g 3=o (PyTorch gate order)
    const int row = tn * 16 + b;
#pragma unroll
    for (int j = 0; j < 8; ++j) {
      const int k = 8 * g + j;
      if (k < 18) {
        const float w = Wih1[row * 18 + k];
        A1h[tn].u[j] = f2bf(w);
        A1l[tn].u[j] = f2bf(w - bfbits2f(A1h[tn].u[j]));
      } else {
        A1h[tn].u[j] = 0;
        A1l[tn].u[j] = 0;
      }
      const int kk = k >> 1;  // hi/lo interleave: both K slots share the weight
      const float w2 = Whh1[row * 16 + kk];
      const float w3 = Wih2[row * 16 + kk];
      const float w4 = Whh2[row * 16 + kk];
      A2h[tn].u[j] = f2bf(w2); A2l[tn].u[j] = f2bf(w2 - bfbits2f(A2h[tn].u[j]));
      A3h[tn].u[j] = f2bf(w3); A3l[tn].u[j] = f2bf(w3 - bfbits2f(A3h[tn].u[j]));
      A4h[tn].u[j] = f2bf(w4); A4l[tn].u[j] = f2bf(w4 - bfbits2f(A4h[tn].u[j]));
    }
#pragma unroll
    for (int r = 0; r < 4; ++r) {
      const int u4 = tn * 16 + 4 * g + r;  // C row = unit 4g+r of gate tn
      bias1v[tn][r] = bih1[u4] + bhh1[u4];
      bias2v[tn][r] = bih2[u4] + bhh2[u4];
    }
  }

  // ---- x addressing: lane (b,g) covers x[b0+b][t][8g .. 8g+7] ----
  // g==3 lanes: k=24..31 are all beyond I=18; their B-slots multiply zero
  // weights (A1 pad), so they read a fixed valid address and never advance.
  const float* const x0 = x + (size_t)(b0 + b) * 1800 + 8 * g;
  const int adv = (g == 3) ? 0 : 18;

  auto loadraw = [&](const float* p) -> RawX {
    RawX r;
    r.a = *(const float2*)p;  // g<2: k 8g..8g+1; g==2: k 16,17; g==3: dummy
    if (g < 2) {              // full 8 features, in-bounds for all t
      r.b2 = *(const float2*)(p + 2);
      r.c  = *(const float2*)(p + 4);
      r.d  = *(const float2*)(p + 6);
    } else {                  // g>=2: only pair a matters (k>=18 hits A-pad)
      r.b2 = r.c = r.d = make_float2(0.f, 0.f);
    }
    return r;
  };
  auto cvt = [&](const RawX& rw_, FragU& hi, FragU& lo) {
    cvt_pair(rw_.a.x, rw_.a.y, hi.d[0], lo.d[0]);
    cvt_pair(rw_.b2.x, rw_.b2.y, hi.d[1], lo.d[1]);
    cvt_pair(rw_.c.x, rw_.c.y, hi.d[2], lo.d[2]);
    cvt_pair(rw_.d.x, rw_.d.y, hi.d[3], lo.d[3]);
  };

  // ---- prologue: raw x for t=0,1,2 in flight together ----
  RawX rw0 = loadraw(x0);
  RawX rw1 = loadraw(x0 + adv);
  RawX rw  = loadraw(x0 + 2 * adv);
  const float* xq = x0 + 3 * adv;  // next load target: t=3

  FragU hb, h2b;
  hb.q  = (uint32x4){0u, 0u, 0u, 0u};  // h1_{-1}
  h2b.q = (uint32x4){0u, 0u, 0u, 0u};  // h2_{-1}
  float c1[4] = {0.f, 0.f, 0.f, 0.f};
  float c2[4] = {0.f, 0.f, 0.f, 0.f};

  FragU xch, xcl;
  cvt(rw0, xch, xcl);  // x(0)

  // ga = L1 gate preacts for t=0 (hb = 0); R6's exact tn-major 5-chain
  f32x4 ga[4];
#pragma unroll
  for (int tn = 0; tn < 4; ++tn) {
    f32x4 acc = MFMA16(A1h[tn].v, xch.v, bias1v[tn]);
    acc = MFMA16(A1l[tn].v, xch.v, acc);
    acc = MFMA16(A1h[tn].v, xcl.v, acc);
    acc = MFMA16(A2h[tn].v, hb.v, acc);
    acc = MFMA16(A2l[tn].v, hb.v, acc);
    ga[tn] = acc;
  }
  cvt(rw1, xch, xcl);  // x(1) ready for the loop's L1-MFMAs(t+1)

  // gb = dummy L2 preacts for "t = -1": yields EXACT h2=0, c2=0.
  // sigm(-1e3) = rcp(1+exp2(1442.7)) = rcp(inf) = 0; tanh_(0) = 0.
  f32x4 gb[4];
  gb[0] = (f32x4){-1e3f, -1e3f, -1e3f, -1e3f};  // i -> 0
  gb[1] = gb[0];                                // f -> 0 (c2 starts 0 anyway)
  gb[2] = (f32x4){0.f, 0.f, 0.f, 0.f};          // g -> tanh(0) = 0
  gb[3] = gb[0];                                // o -> 0

#pragma unroll 2
  for (int t = 0; t < 100; ++t) {
    // ---- (1) L1 ew (t)  ||  L2 ew (t-1): 8 INDEPENDENT trans cells ----
    // Interleaved in one r-loop so the scheduler overlaps their exp2/rcp
    // dependency chains; this was R6's 2x serialized latency block.
    FragU rb;
#pragma unroll
    for (int r = 0; r < 4; ++r) {
      // L1 cell r (step t): ga -> hb, rb
      const float iv = sigm(ga[0][r]);
      const float fv = sigm(ga[1][r]);
      const float gv = tanh_(ga[2][r]);
      const float ov = sigm(ga[3][r]);
      const float cc = fv * c1[r] + iv * gv;
      c1[r] = cc;
      const float h = ov * tanh_(cc);
      const unsigned int pk = split_pack(h);
      hb.d[r] = pk;
      rb.d[r] = (h > 0.f) ? pk : 0u;  // relu: identical split when positive
      // L2 cell r (step t-1): gb -> h2b   [fully independent of L1 cell]
      const float iv2 = sigm(gb[0][r]);
      const float fv2 = sigm(gb[1][r]);
      const float gv2 = tanh_(gb[2][r]);
      const float ov2 = sigm(gb[3][r]);
      const float dd = fv2 * c2[r] + iv2 * gv2;
      c2[r] = dd;
      const float h2 = ov2 * tanh_(dd);
      h2b.d[r] = split_pack(h2);
    }

    // ---- (2) L2 MFMAs (t): h2b (fresh, = h2(t-1)) and rb (fresh) ----
    // tn-major chains exactly as R6 (R10 proved reordering hurts).
    f32x4 gbn[4];
#pragma unroll
    for (int tn = 0; tn < 4; ++tn) {
      f32x4 acc = MFMA16(A4h[tn].v, h2b.v, bias2v[tn]);
      acc = MFMA16(A4l[tn].v, h2b.v, acc);
      acc = MFMA16(A3h[tn].v, rb.v, acc);
      acc = MFMA16(A3l[tn].v, rb.v, acc);
      gbn[tn] = acc;
    }

    // ---- (3) L1 MFMAs (t+1): xch = x(t+1), hb = h1(t) ----
    f32x4 gan[4];
#pragma unroll
    for (int tn = 0; tn < 4; ++tn) {
      f32x4 acc = MFMA16(A1h[tn].v, xch.v, bias1v[tn]);
      acc = MFMA16(A1l[tn].v, xch.v, acc);
      acc = MFMA16(A1h[tn].v, xcl.v, acc);
      acc = MFMA16(A2h[tn].v, hb.v, acc);
      acc = MFMA16(A2l[tn].v, hb.v, acc);
      gan[tn] = acc;
    }

    // ---- (4) convert x(t+2) from raw regs (loaded 2 iters ago) ----
    FragU nxh, nxl;
    cvt(rw, nxh, nxl);

    // ---- (5) issue raw load x(t+3); uniform guard past the end ----
    RawX rwn = loadraw((t <= 96) ? xq : x0);
    xq += adv;

    // rotate pipeline registers (elided by unroll-2 ping-pong)
#pragma unroll
    for (int tn = 0; tn < 4; ++tn) { ga[tn] = gan[tn]; gb[tn] = gbn[tn]; }
    xch = nxh;
    xcl = nxl;
    rw = rwn;
  }

  // ---- epilogue: L2 ew (99) -> relu(h2_last) ----
  // lane (b,g) holds units 4g..4g+3 of batch b.
  f32x4 o;
#pragma unroll
  for (int r = 0; r < 4; ++r) {
    const float iv2 = sigm(gb[0][r]);
    const float fv2 = sigm(gb[1][r]);
    const float gv2 = tanh_(gb[2][r]);
    const float ov2 = sigm(gb[3][r]);
    const float dd = fv2 * c2[r] + iv2 * gv2;
    const float h2 = ov2 * tanh_(dd);
    o[r] = fmaxf(h2, 0.f);
  }
  *(f32x4*)(out + (size_t)(b0 + b) * 16 + 4 * g) = o;  // 16B-aligned

  (void)x0;
}

extern "C" void kernel_launch(void* const* d_in, const int* in_sizes, int n_in,
                              void* d_out, int out_size, void* d_ws, size_t ws_size,
                              hipStream_t stream) {
  (void)in_sizes; (void)n_in; (void)d_ws; (void)ws_size; (void)out_size;
  // 16384 batch / 16 per wave / 4 waves per block = 256 blocks (1 per CU).
  enc_kernel<<<dim3(256), dim3(256), 0, stream>>>(
      (const float*)d_in[0],
      (const float*)d_in[1],
      (const float*)d_in[2],
      (const float*)d_in[3],
      (const float*)d_in[4],
      (const float*)d_in[5],
      (const float*)d_in[6],
      (const float*)d_in[7],
      (const float*)d_in[8],
      (float*)d_out);
}

// Round 6
// 271.859 us; speedup vs baseline: 1.1218x; 1.0044x over previous
//
#include <hip/hip_runtime.h>

// Encoder: 2-layer LSTM (H=16 each), x [B=16384, T=100, I=18], FP32 in/out.
// R12: R6 structure verbatim (best measured 141.6us) with ONE change: the
// LSTM cell math merges reciprocals. Model (fits R6/R7/R9/R11 counters):
// VALUBusy ~= trans-issue occupancy; 80 trans/iter x ~16cy = 1280cy is the
// largest wall component; the kernel is TRANS-ISSUE-BOUND. R10/R11 proved
// reordering/merging does nothing (issue, not latency). So reduce count:
//   cc = fv*c + iv*gv = [c*P + (gE-1)(1+bE)] * rcp((1+bE)*P),  P=(1+a)(1+gE)
//   h  = ov*tanh(cc)  = (cE-1) * rcp((1+dE)(1+cE))
// -> 5 exp2 + 2 rcp = 7 trans/cell (was 10). -24 trans/iter ~= -380cy.
// Overflow-safe: preact std ~0.6 (w~U(+-0.25), 16-18 terms); worst-case
// exp2 args << 128 even at 5.5-sigma inputs; products < 2^108 < fp32 max.
// NOT bit-identical to R6 (algebraic rearrangement, few-ulp fp32); error
// structure unchanged; expect absmax ~1e-3 vs 3.9e-3 threshold.
// Everything else R6: one wave per 16-batch tile (1024 waves = 1/SIMD),
// tn-major MFMA chains, packed (hi|lo<<16) h dwords ARE the next step's
// B-fragment, pipeline L1ew -> L2-MFMA -> L1-MFMA(t+1) -> cvt -> load -> L2ew.

typedef float f32x4 __attribute__((ext_vector_type(4)));
typedef __bf16 bf16x8 __attribute__((ext_vector_type(8)));
typedef unsigned int uint32x4 __attribute__((ext_vector_type(4)));

union FragU { bf16x8 v; unsigned short u[8]; unsigned int d[4]; uint32x4 q; };

#define MFMA16(A, B, C) __builtin_amdgcn_mfma_f32_16x16x32_bf16((A), (B), (C), 0, 0, 0)

static __device__ __forceinline__ unsigned short f2bf(float f) {  // RNE (weights)
  unsigned int u = __builtin_bit_cast(unsigned int, f);
  u = u + 0x7FFFu + ((u >> 16) & 1u);
  return (unsigned short)(u >> 16);
}
static __device__ __forceinline__ float bfbits2f(unsigned short h) {
  unsigned int u = ((unsigned int)h) << 16;
  return __builtin_bit_cast(float, u);
}
// Merged-rcp LSTM cell: i,f,g,o preacts + c-state -> h (updates c).
//   iv=1/(1+a), fv=1/(1+bE), gv=(gE-1)/(gE+1), ov=1/(1+dE), tanh=(cE-1)/(cE+1)
//   cc = fv*c + iv*gv  computed over common denominator with ONE rcp
//   h  = ov*tanh(cc)   computed with ONE rcp
// 5 exp2 + 2 rcp = 7 trans (was 10). Mathematically identical to
// sigm/tanh_ composition; fp32 rounding differs by a few ulp.
static __device__ __forceinline__ float lstm_cell(float ipre, float fpre,
                                                  float gpre, float opre,
                                                  float& c) {
  const float a  = __builtin_amdgcn_exp2f(ipre * -1.4426950408889634f);  // e^-i
  const float bE = __builtin_amdgcn_exp2f(fpre * -1.4426950408889634f);  // e^-f
  const float gE = __builtin_amdgcn_exp2f(gpre *  2.8853900817779268f);  // e^{2g}
  const float dE = __builtin_amdgcn_exp2f(opre * -1.4426950408889634f);  // e^-o
  const float B1 = 1.0f + bE;
  const float P  = (1.0f + a) * (1.0f + gE);
  const float num = fmaf(c, P, (gE - 1.0f) * B1);
  const float cc = num * __builtin_amdgcn_rcpf(P * B1);
  c = cc;
  const float cE = __builtin_amdgcn_exp2f(cc * 2.8853900817779268f);     // e^{2cc}
  return (cE - 1.0f) * __builtin_amdgcn_rcpf((1.0f + dE) * (1.0f + cE));
}
// Trunc two-term split packed as (bf_hi | bf_lo<<16), via v_perm_b32:
// D bytes {l[3],l[2],u[3],u[2]} == (u>>16) | (l & 0xFFFF0000). Bit-exact.
static __device__ __forceinline__ unsigned int split_pack(float v) {
  unsigned int u = __builtin_bit_cast(unsigned int, v);
  float hf = __builtin_bit_cast(float, u & 0xFFFF0000u);
  unsigned int l = __builtin_bit_cast(unsigned int, v - hf);
  return __builtin_amdgcn_perm(l, u, 0x07060302u);
}
// Split a float pair into hi-frag dword and lo-frag dword (6 VALU via perm).
static __device__ __forceinline__ void cvt_pair(float f0, float f1,
                                                unsigned int& hd, unsigned int& ld) {
  unsigned int u0 = __builtin_bit_cast(unsigned int, f0);
  unsigned int u1 = __builtin_bit_cast(unsigned int, f1);
  unsigned int h0 = u0 & 0xFFFF0000u;
  unsigned int h1 = u1 & 0xFFFF0000u;
  hd = __builtin_amdgcn_perm(u1, u0, 0x07060302u);
  unsigned int l0 = __builtin_bit_cast(unsigned int, f0 - __builtin_bit_cast(float, h0));
  unsigned int l1 = __builtin_bit_cast(unsigned int, f1 - __builtin_bit_cast(float, h1));
  ld = __builtin_amdgcn_perm(l1, l0, 0x07060302u);
}

struct RawX { float2 a, b2, c, d; };

__global__ __launch_bounds__(256, 1) void enc_kernel(
    const float* __restrict__ x,     // [16384,100,18]
    const float* __restrict__ Wih1,  // [64,18]
    const float* __restrict__ Whh1,  // [64,16]
    const float* __restrict__ bih1,  // [64]
    const float* __restrict__ bhh1,  // [64]
    const float* __restrict__ Wih2,  // [64,16]
    const float* __restrict__ Whh2,  // [64,16]
    const float* __restrict__ bih2,  // [64]
    const float* __restrict__ bhh2,  // [64]
    float* __restrict__ out)         // [16384,16]
{
  const int lane = threadIdx.x & 63;
  const int b    = lane & 15;  // batch in tile: A m-row / B n-col / C col
  const int g    = lane >> 4;  // k-group; C row-quad (units 4g..4g+3)

  const int wid = (int)((blockIdx.x * blockDim.x + threadIdx.x) >> 6);
  const int b0  = wid * 16;

  // ---- loop-invariant weight A-fragments: A[m=lane&15][k=8g+j] ----
  FragU A1h[4], A1l[4], A2h[4], A2l[4], A3h[4], A3l[4], A4h[4], A4l[4];
  f32x4 bias1v[4], bias2v[4];
#pragma unroll
  for (int tn = 0; tn < 4; ++tn) {  // 0=i 1=f 2=g 3=o (PyTorch gate order)
    const int row = tn * 16 + b;
#pragma unroll
    for (int j = 0; j < 8; ++j) {
      const int k = 8 * g + j;
      if (k < 18) {
        const float w = Wih1[row * 18 + k];
        A1h[tn].u[j] = f2bf(w);
        A1l[tn].u[j] = f2bf(w - bfbits2f(A1h[tn].u[j]));
      } else {
        A1h[tn].u[j] = 0;
        A1l[tn].u[j] = 0;
      }
      const int kk = k >> 1;  // hi/lo interleave: both K slots share the weight
      const float w2 = Whh1[row * 16 + kk];
      const float w3 = Wih2[row * 16 + kk];
      const float w4 = Whh2[row * 16 + kk];
      A2h[tn].u[j] = f2bf(w2); A2l[tn].u[j] = f2bf(w2 - bfbits2f(A2h[tn].u[j]));
      A3h[tn].u[j] = f2bf(w3); A3l[tn].u[j] = f2bf(w3 - bfbits2f(A3h[tn].u[j]));
      A4h[tn].u[j] = f2bf(w4); A4l[tn].u[j] = f2bf(w4 - bfbits2f(A4h[tn].u[j]));
    }
#pragma unroll
    for (int r = 0; r < 4; ++r) {
      const int u4 = tn * 16 + 4 * g + r;  // C row = unit 4g+r of gate tn
      bias1v[tn][r] = bih1[u4] + bhh1[u4];
      bias2v[tn][r] = bih2[u4] + bhh2[u4];
    }
  }

  // ---- x addressing: lane (b,g) covers x[b0+b][t][8g .. 8g+7] ----
  // g==3 lanes: k=24..31 are all beyond I=18; their B-slots multiply zero
  // weights (A1 pad), so they read a fixed valid address and never advance.
  const float* const x0 = x + (size_t)(b0 + b) * 1800 + 8 * g;
  const int adv = (g == 3) ? 0 : 18;

  auto loadraw = [&](const float* p) -> RawX {
    RawX r;
    r.a = *(const float2*)p;  // g<2: k 8g..8g+1; g==2: k 16,17; g==3: dummy
    if (g < 2) {              // full 8 features, in-bounds for all t
      r.b2 = *(const float2*)(p + 2);
      r.c  = *(const float2*)(p + 4);
      r.d  = *(const float2*)(p + 6);
    } else {                  // g>=2: only pair a matters (k>=18 hits A-pad)
      r.b2 = r.c = r.d = make_float2(0.f, 0.f);
    }
    return r;
  };
  auto cvt = [&](const RawX& rw_, FragU& hi, FragU& lo) {
    cvt_pair(rw_.a.x, rw_.a.y, hi.d[0], lo.d[0]);
    cvt_pair(rw_.b2.x, rw_.b2.y, hi.d[1], lo.d[1]);
    cvt_pair(rw_.c.x, rw_.c.y, hi.d[2], lo.d[2]);
    cvt_pair(rw_.d.x, rw_.d.y, hi.d[3], lo.d[3]);
  };

  // ---- prologue: raw x for t=0,1,2 in flight together ----
  RawX rw0 = loadraw(x0);
  RawX rw1 = loadraw(x0 + adv);
  RawX rw  = loadraw(x0 + 2 * adv);
  const float* xq = x0 + 3 * adv;  // next load target: t=3

  FragU hb, h2b;
  hb.q  = (uint32x4){0u, 0u, 0u, 0u};  // h1_{-1}
  h2b.q = (uint32x4){0u, 0u, 0u, 0u};  // h2_{-1}
  float c1[4] = {0.f, 0.f, 0.f, 0.f};
  float c2[4] = {0.f, 0.f, 0.f, 0.f};
  float h2v[4] = {0.f, 0.f, 0.f, 0.f};

  FragU xch, xcl;
  cvt(rw0, xch, xcl);  // x(0)

  // ga = L1 gate preacts for t=0 (hb = 0); R6's exact tn-major 5-chain
  f32x4 ga[4];
#pragma unroll
  for (int tn = 0; tn < 4; ++tn) {
    f32x4 acc = MFMA16(A1h[tn].v, xch.v, bias1v[tn]);
    acc = MFMA16(A1l[tn].v, xch.v, acc);
    acc = MFMA16(A1h[tn].v, xcl.v, acc);
    acc = MFMA16(A2h[tn].v, hb.v, acc);
    acc = MFMA16(A2l[tn].v, hb.v, acc);
    ga[tn] = acc;
  }
  cvt(rw1, xch, xcl);  // x(1) ready for the loop's L1-MFMAs(t+1)

#pragma unroll 2
  for (int t = 0; t < 100; ++t) {
    // ---- (1) L1 elementwise (t): ga -> h1(t) as packed hi/lo ----
    FragU rb;
#pragma unroll
    for (int r = 0; r < 4; ++r) {
      const float h = lstm_cell(ga[0][r], ga[1][r], ga[2][r], ga[3][r], c1[r]);
      const unsigned int pk = split_pack(h);
      hb.d[r] = pk;
      rb.d[r] = (h > 0.f) ? pk : 0u;  // relu: identical split when positive
    }

    // ---- (2) L2 MFMAs (t): uses rb (fresh) and h2b = h2(t-1) ----
    f32x4 gb[4];
#pragma unroll
    for (int tn = 0; tn < 4; ++tn) {
      f32x4 acc = MFMA16(A4h[tn].v, h2b.v, bias2v[tn]);
      acc = MFMA16(A4l[tn].v, h2b.v, acc);
      acc = MFMA16(A3h[tn].v, rb.v, acc);
      acc = MFMA16(A3l[tn].v, rb.v, acc);
      gb[tn] = acc;
    }

    // ---- (3) L1 MFMAs (t+1): independent of gb; hides MFMA latency ----
    f32x4 gan[4];
#pragma unroll
    for (int tn = 0; tn < 4; ++tn) {
      f32x4 acc = MFMA16(A1h[tn].v, xch.v, bias1v[tn]);
      acc = MFMA16(A1l[tn].v, xch.v, acc);
      acc = MFMA16(A1h[tn].v, xcl.v, acc);
      acc = MFMA16(A2h[tn].v, hb.v, acc);
      acc = MFMA16(A2l[tn].v, hb.v, acc);
      gan[tn] = acc;
    }

    // ---- (4) convert x(t+2) from raw regs (loaded 2 iters ago) ----
    FragU nxh, nxl;
    cvt(rw, nxh, nxl);

    // ---- (5) issue raw load x(t+3); uniform guard past the end ----
    RawX rwn = loadraw((t <= 96) ? xq : x0);
    xq += adv;

    // ---- (6) L2 elementwise (t): gb arrived long ago ----
#pragma unroll
    for (int r = 0; r < 4; ++r) {
      const float h = lstm_cell(gb[0][r], gb[1][r], gb[2][r], gb[3][r], c2[r]);
      h2v[r] = h;
      h2b.d[r] = split_pack(h);
    }

    // rotate pipeline registers (elided by unroll-2 ping-pong)
#pragma unroll
    for (int tn = 0; tn < 4; ++tn) ga[tn] = gan[tn];
    xch = nxh;
    xcl = nxl;
    rw = rwn;
  }

  // ---- output: relu(h2_last); lane (b,g) holds units 4g..4g+3 of batch b ----
  f32x4 o;
#pragma unroll
  for (int r = 0; r < 4; ++r) o[r] = fmaxf(h2v[r], 0.f);
  *(f32x4*)(out + (size_t)(b0 + b) * 16 + 4 * g) = o;  // 16B-aligned

  (void)x0;
}

extern "C" void kernel_launch(void* const* d_in, const int* in_sizes, int n_in,
                              void* d_out, int out_size, void* d_ws, size_t ws_size,
                              hipStream_t stream) {
  (void)in_sizes; (void)n_in; (void)d_ws; (void)ws_size; (void)out_size;
  // 16384 batch / 16 per wave / 4 waves per block = 256 blocks (1 per CU).
  enc_kernel<<<dim3(256), dim3(256), 0, stream>>>(
      (const float*)d_in[0],
      (const float*)d_in[1],
      (const float*)d_in[2],
      (const float*)d_in[3],
      (const float*)d_in[4],
      (const float*)d_in[5],
      (const float*)d_in[6],
      (const float*)d_in[7],
      (const float*)d_in[8],
      (float*)d_out);
}